// Round 7
// baseline (145.523 us; speedup 1.0000x reference)
//
#include <hip/hip_runtime.h>
#include <hip/hip_bf16.h>

// MahalanobisDistanceLayer: B=8192, D=64.
// q = E @ E^T with E = (a-b) * rsqrt(var_per_feature(concat(a,b)+eps));
// out[i] = sum_j (q<0 ? 0 : sqrt(q)) + B*EPS_OUT for (anchor,positive), (anchor,negative).
//
// Split-bf16: E = Ehi + Elo. q ~= Ehi*Ehi^T + Ehi*Elo^T + Elo*Ehi^T -> K=192 bf16 GEMM.
// Symmetric scheme: per pair, 64 tiles of 128 rows; unordered tile pair {ib, (ib+s)&63}
// processed exactly once (s in [0,32], s=32 only for ib<32). Off-diag tiles contribute
// row-sums to ib-rows AND col-sums to jb-rows (f(q) symmetric) -> half the FLOPs.
// s-list split across (half, squad): s = half + 2*squad + 4*t -> 512 blocks = 2/CU.

typedef short bf16x8 __attribute__((ext_vector_type(8)));
typedef unsigned short u16x8 __attribute__((ext_vector_type(8)));
typedef float f32x4 __attribute__((ext_vector_type(4)));

#define BROWS 8192
#define DFEAT 64
#define NCO   16384
#define EPS_IN  1e-4f
#define EPS_OUT 1e-6f

// ---- workspace layout (bytes) ----
// [0, 1536)        : stats, 6 groups x 64 floats (Sa,Qa,Sp,Qp,Sn,Qn), atomic-accumulated
// [2048, 2048+4MB) : EHL, 2 pairs x 8192 rows x 128 bf16 (row = [hi(64)|lo(64)], 256B)
//                    16B-chunk index XOR-swizzled by (row&7)
#define WS_EHL_F 512
#define EHL_PAIR_USHORTS ((size_t)BROWS * 128)

static __device__ inline unsigned short f2bf_rne(float x) {
  unsigned u = __float_as_uint(x);
  unsigned r = (u + 0x7FFF + ((u >> 16) & 1)) >> 16;
  return (unsigned short)r;
}
static __device__ inline float bf2f(unsigned short s) {
  return __uint_as_float(((unsigned)s) << 16);
}

// ---------------------------------------------------------------------------
// Kernel A: per-feature sums / sums-of-squares, float4 loads, atomic into stats[384].
// 256 blocks x 256 threads; each thread loads 2 float4 per array.
__global__ __launch_bounds__(256) void stats_kernel(
    const float* __restrict__ a, const float* __restrict__ p,
    const float* __restrict__ n, float* __restrict__ stats) {
  __shared__ float acc[6][64];
  int tid = threadIdx.x;
  for (int v = tid; v < 384; v += 256) acc[v >> 6][v & 63] = 0.f;
  __syncthreads();
  const float4* A4 = (const float4*)a;
  const float4* P4 = (const float4*)p;
  const float4* N4 = (const float4*)n;
  size_t base = (size_t)blockIdx.x * 512 + tid;
  float s[3][4] = {}, q[3][4] = {};
  #pragma unroll
  for (int k = 0; k < 2; ++k) {
    size_t idx = base + k * 256;
    float4 va = A4[idx], vp = P4[idx], vn = N4[idx];
    float ea[4] = {va.x, va.y, va.z, va.w};
    float ep[4] = {vp.x, vp.y, vp.z, vp.w};
    float en[4] = {vn.x, vn.y, vn.z, vn.w};
    #pragma unroll
    for (int f = 0; f < 4; ++f) {
      float x0 = ea[f] + EPS_IN; s[0][f] += x0; q[0][f] += x0 * x0;
      float x1 = ep[f] + EPS_IN; s[1][f] += x1; q[1][f] += x1 * x1;
      float x2 = en[f] + EPS_IN; s[2][f] += x2; q[2][f] += x2 * x2;
    }
  }
  // lanes t, t^16, t^32, t^48 share the same feature group d0 = 4*(t&15)
  #pragma unroll
  for (int g = 0; g < 3; ++g)
    #pragma unroll
    for (int f = 0; f < 4; ++f) {
      float vs = s[g][f], vq = q[g][f];
      vs += __shfl_xor(vs, 16); vs += __shfl_xor(vs, 32);
      vq += __shfl_xor(vq, 16); vq += __shfl_xor(vq, 32);
      s[g][f] = vs; q[g][f] = vq;
    }
  int lane = tid & 63;
  if (lane < 16) {
    int d0 = lane * 4;
    #pragma unroll
    for (int g = 0; g < 3; ++g)
      #pragma unroll
      for (int f = 0; f < 4; ++f) {
        atomicAdd(&acc[2 * g][d0 + f], s[g][f]);
        atomicAdd(&acc[2 * g + 1][d0 + f], q[g][f]);
      }
  }
  __syncthreads();
  for (int v = tid; v < 384; v += 256)
    atomicAdd(&stats[v], acc[v >> 6][v & 63]);
}

// ---------------------------------------------------------------------------
// Kernel B: inline inv_std from stats; build EHL rows [hi(64)|lo(64)] bf16,
// 16B chunks XOR-swizzled by row&7. Also pre-loads out with 8192*EPS_OUT.
// Grid: 2 pairs x 256 row-tiles (32 rows each) = 512 blocks x 256 threads.
__global__ __launch_bounds__(256) void prep_kernel(
    const float* __restrict__ a, const float* __restrict__ p,
    const float* __restrict__ n, const float* __restrict__ stats,
    unsigned short* __restrict__ EHL, float* __restrict__ out) {
  __shared__ float is_s[64];
  int pair = blockIdx.x >> 8;
  int tb   = blockIdx.x & 255;
  int tid  = threadIdx.x;
  if (tid < 32) out[blockIdx.x * 32 + tid] = 8192.0f * EPS_OUT;
  if (tid < 64) {
    float sa = stats[tid], qa = stats[64 + tid];
    float sb = pair ? stats[256 + tid] : stats[128 + tid];
    float qb = pair ? stats[320 + tid] : stats[192 + tid];
    const float invN = 1.0f / (float)NCO;
    float m = (sa + sb) * invN;
    float v = (qa + qb) * invN - m * m;
    is_s[tid] = 1.0f / sqrtf(v);
  }
  __syncthreads();
  const float* bptr = pair ? n : p;
  unsigned short* dst = EHL + (size_t)pair * EHL_PAIR_USHORTS;
  int c0 = tid & 7;          // chunk within row (8 bf16 = 16B)
  int rl = tid >> 3;         // row within block (0..31)
  int row = tb * 32 + rl;
  int d0 = c0 * 8;
  const float* ar = a    + (size_t)row * DFEAT + d0;
  const float* br = bptr + (size_t)row * DFEAT + d0;
  float4 a0 = *(const float4*)(ar);
  float4 a1 = *(const float4*)(ar + 4);
  float4 b0 = *(const float4*)(br);
  float4 b1 = *(const float4*)(br + 4);
  float e[8] = {a0.x - b0.x, a0.y - b0.y, a0.z - b0.z, a0.w - b0.w,
                a1.x - b1.x, a1.y - b1.y, a1.z - b1.z, a1.w - b1.w};
  u16x8 vh, vl;
  #pragma unroll
  for (int j = 0; j < 8; ++j) {
    float ej = e[j] * is_s[d0 + j];
    unsigned short hi = f2bf_rne(ej);
    vh[j] = hi;
    vl[j] = f2bf_rne(ej - bf2f(hi));
  }
  int cs = c0 ^ (row & 7);
  char* drow = (char*)dst + (size_t)row * 256;
  *(u16x8*)(drow + cs * 16)       = vh;   // hi chunk
  *(u16x8*)(drow + (8 + cs) * 16) = vl;   // lo chunk
}

// ---------------------------------------------------------------------------
// Kernel C: symmetric MFMA GEMM. 128x128 tiles, 8 waves (2x4) of 64x32.
// Persistent A-frags in registers; sX reused as second B buffer after af load.
// Grid: 2 pairs x 64 ib x 2 half x 2 squad = 512 blocks (2/CU), 512 threads.
#define GLOAD(gsrc, ldst)                                                  \
  __builtin_amdgcn_global_load_lds(                                        \
      (const __attribute__((address_space(1))) void*)(gsrc),               \
      (__attribute__((address_space(3))) void*)(ldst), 16, 0, 0)

__global__ __launch_bounds__(512, 4) void mdist_mfma(
    const unsigned short* __restrict__ EHL, float* __restrict__ out) {
  __shared__ __align__(16) unsigned char sX[32768];   // A tile, then B buffer
  __shared__ __align__(16) unsigned char sY[32768];   // B buffer
  int bid = blockIdx.x;
  int sw  = (bid & 7) * 64 + (bid >> 3);   // bijective XCD swizzle (512 = 8*64)
  int pair  = sw >> 8;
  int ib    = (sw >> 2) & 63;
  int half  = (sw >> 1) & 1;
  int squad = sw & 1;
  const char* base = (const char*)(EHL + (size_t)pair * EHL_PAIR_USHORTS);
  const char* gA = base + (size_t)ib * 32768;
  int tid = threadIdx.x;
  int s0   = half + 2 * squad;             // 0..3
  int smax = (ib < 32) ? 32 : 31;

  // prologue: A -> sX, B(s0) -> sY
  {
    int jb0 = (ib + s0) & 63;
    const char* gB0 = base + (size_t)jb0 * 32768;
    #pragma unroll
    for (int r = 0; r < 4; ++r) {
      int off = r * 8192 + tid * 16;
      GLOAD(gA + off, sX + off);
      GLOAD(gB0 + off, sY + off);
    }
  }
  __syncthreads();

  int lane = tid & 63, w = tid >> 6;
  int wr = w >> 2, wc = w & 3;             // wave tile: rows wr*64+.., cols wc*32+..
  int l15 = lane & 15, lg = lane >> 4;

  // A fragments, resident for whole kernel: af[hk][m], hk = (half_sel<<1)|ks
  bf16x8 af[4][4];
  #pragma unroll
  for (int hk = 0; hk < 4; ++hk) {
    int c = ((hk >> 1) << 3) | ((hk & 1) << 2) | lg;
    #pragma unroll
    for (int m = 0; m < 4; ++m) {
      int r = wr * 64 + m * 16 + l15;
      int cs = c ^ (r & 7);
      af[hk][m] = *(const bf16x8*)(sX + r * 256 + cs * 16);
    }
  }
  __syncthreads();   // all af reads done -> sX free for B staging

  float rs[4][4];
  #pragma unroll
  for (int m = 0; m < 4; ++m)
    #pragma unroll
    for (int r = 0; r < 4; ++r) rs[m][r] = 0.f;

  const f32x4 zacc = {0.f, 0.f, 0.f, 0.f};
  const int AH[3] = {0, 0, 1};
  const int BH[3] = {0, 1, 0};
  int cur = 1;                             // sY holds current B

  for (int s = s0; s <= smax; s += 4) {
    unsigned char* wbuf = cur ? sX : sY;
    const unsigned char* rbuf = cur ? sY : sX;
    int snext = s + 4;
    if (snext <= smax) {
      int jbn = (ib + snext) & 63;
      const char* gs = base + (size_t)jbn * 32768;
      #pragma unroll
      for (int r = 0; r < 4; ++r) {
        int off = r * 8192 + tid * 16;
        GLOAD(gs + off, wbuf + off);
      }
    }
    // B fragments for this step
    bf16x8 bf[4][2];
    #pragma unroll
    for (int hk = 0; hk < 4; ++hk) {
      int c = ((hk >> 1) << 3) | ((hk & 1) << 2) | lg;
      #pragma unroll
      for (int nn = 0; nn < 2; ++nn) {
        int r = wc * 32 + nn * 16 + l15;
        int cs = c ^ (r & 7);
        bf[hk][nn] = *(const bf16x8*)(rbuf + r * 256 + cs * 16);
      }
    }
    // 48 MFMAs, K=192, fresh accumulator each step
    f32x4 acc[4][2];
    #pragma unroll
    for (int t = 0; t < 3; ++t) {
      #pragma unroll
      for (int ks = 0; ks < 2; ++ks) {
        int ahk = (AH[t] << 1) | ks;
        int bhk = (BH[t] << 1) | ks;
        #pragma unroll
        for (int m = 0; m < 4; ++m) {
          #pragma unroll
          for (int nn = 0; nn < 2; ++nn)
            acc[m][nn] = __builtin_amdgcn_mfma_f32_16x16x32_bf16(
                af[ahk][m], bf[bhk][nn],
                (t == 0 && ks == 0) ? zacc : acc[m][nn], 0, 0, 0);
        }
      }
    }
    // epilogue: f = sqrt(max(q,0)); rows always; cols for off-diag tiles
    if (s == 0) {
      #pragma unroll
      for (int m = 0; m < 4; ++m)
        #pragma unroll
        for (int nn = 0; nn < 2; ++nn)
          #pragma unroll
          for (int r = 0; r < 4; ++r)
            rs[m][r] += __builtin_amdgcn_sqrtf(fmaxf(acc[m][nn][r], 0.f));
    } else {
      float cq0 = 0.f, cq1 = 0.f;
      #pragma unroll
      for (int m = 0; m < 4; ++m)
        #pragma unroll
        for (int nn = 0; nn < 2; ++nn)
          #pragma unroll
          for (int r = 0; r < 4; ++r) {
            float f = __builtin_amdgcn_sqrtf(fmaxf(acc[m][nn][r], 0.f));
            rs[m][r] += f;
            if (nn == 0) cq0 += f; else cq1 += f;
          }
      // reduce col sums over the row-lane groups (lg dimension)
      cq0 += __shfl_xor(cq0, 16); cq0 += __shfl_xor(cq0, 32);
      cq1 += __shfl_xor(cq1, 16); cq1 += __shfl_xor(cq1, 32);
      if (lane < 16) {
        int jb = (ib + s) & 63;
        float* orow = &out[pair * BROWS + jb * 128 + wc * 32 + l15];
        atomicAdd(orow, cq0);
        atomicAdd(orow + 16, cq1);
      }
    }
    __syncthreads();
    cur ^= 1;
  }

  // final row-sum reduce over the 16 col-lanes, one atomic per row per wave
  #pragma unroll
  for (int m = 0; m < 4; ++m)
    #pragma unroll
    for (int r = 0; r < 4; ++r) {
      float v = rs[m][r];
      v += __shfl_xor(v, 1);
      v += __shfl_xor(v, 2);
      v += __shfl_xor(v, 4);
      v += __shfl_xor(v, 8);
      rs[m][r] = v;
    }
  if (l15 == 0) {
    int i0 = ib * 128 + wr * 64;
    #pragma unroll
    for (int m = 0; m < 4; ++m)
      #pragma unroll
      for (int r = 0; r < 4; ++r)
        atomicAdd(&out[pair * BROWS + i0 + m * 16 + lg * 4 + r], rs[m][r]);
  }
}

// ---------------------------------------------------------------------------
extern "C" void kernel_launch(void* const* d_in, const int* in_sizes, int n_in,
                              void* d_out, int out_size, void* d_ws, size_t ws_size,
                              hipStream_t stream) {
  const float* anchor   = (const float*)d_in[0];
  const float* positive = (const float*)d_in[1];
  const float* negative = (const float*)d_in[2];
  float* out = (float*)d_out;
  float* ws  = (float*)d_ws;

  float* stats = ws;
  unsigned short* EHL = (unsigned short*)(ws + WS_EHL_F);

  hipMemsetAsync(stats, 0, 384 * sizeof(float), stream);
  stats_kernel<<<256, 256, 0, stream>>>(anchor, positive, negative, stats);
  prep_kernel<<<512, 256, 0, stream>>>(anchor, positive, negative, stats, EHL, out);
  mdist_mfma<<<512, 512, 0, stream>>>(EHL, out);
}

// Round 8
// 106.167 us; speedup vs baseline: 1.3707x; 1.3707x over previous
//
#include <hip/hip_runtime.h>
#include <hip/hip_bf16.h>

// MahalanobisDistanceLayer: B=8192, D=64.
// q = E @ E^T with E = (a-b) * rsqrt(var_per_feature(concat(a,b)+eps));
// out[i] = sum_j (q<0 ? 0 : sqrt(q)) + B*EPS_OUT for (anchor,positive), (anchor,negative).
//
// Split-bf16: E = Ehi + Elo. q ~= Ehi*Ehi^T + Ehi*Elo^T + Elo*Ehi^T -> K=192 bf16 GEMM.
// Symmetric scheme: per pair, 64 tiles of 128 rows; unordered tile pair {ib,(ib+s)&63}
// processed exactly once (s in [0,32], s=32 only for ib<32). Off-diag tiles contribute
// row-sums to ib-rows AND col-sums to jb-rows (f(q) symmetric) -> half the FLOPs.
// Each 128x128 tile pair = two 64-row B substeps (16KB, double-buffered).
// 256-thread blocks, launch_bounds(256,2): round-5's no-spill envelope (VGPR<=256).

typedef short bf16x8 __attribute__((ext_vector_type(8)));
typedef unsigned short u16x8 __attribute__((ext_vector_type(8)));
typedef float f32x4 __attribute__((ext_vector_type(4)));

#define BROWS 8192
#define DFEAT 64
#define NCO   16384
#define EPS_IN  1e-4f
#define EPS_OUT 1e-6f

// ---- workspace layout (bytes) ----
// [0, 1536)        : stats, 6 groups x 64 floats (Sa,Qa,Sp,Qp,Sn,Qn), atomic-accumulated
// [2048, 2048+4MB) : EHL, 2 pairs x 8192 rows x 128 bf16 (row = [hi(64)|lo(64)], 256B)
//                    16B-chunk index XOR-swizzled by (row&7)
#define WS_EHL_F 512
#define EHL_PAIR_USHORTS ((size_t)BROWS * 128)

static __device__ inline unsigned short f2bf_rne(float x) {
  unsigned u = __float_as_uint(x);
  unsigned r = (u + 0x7FFF + ((u >> 16) & 1)) >> 16;
  return (unsigned short)r;
}
static __device__ inline float bf2f(unsigned short s) {
  return __uint_as_float(((unsigned)s) << 16);
}

// ---------------------------------------------------------------------------
// Kernel A: per-feature sums / sums-of-squares, float4 loads, atomic into stats[384].
__global__ __launch_bounds__(256) void stats_kernel(
    const float* __restrict__ a, const float* __restrict__ p,
    const float* __restrict__ n, float* __restrict__ stats) {
  __shared__ float acc[6][64];
  int tid = threadIdx.x;
  for (int v = tid; v < 384; v += 256) acc[v >> 6][v & 63] = 0.f;
  __syncthreads();
  const float4* A4 = (const float4*)a;
  const float4* P4 = (const float4*)p;
  const float4* N4 = (const float4*)n;
  size_t base = (size_t)blockIdx.x * 512 + tid;
  float s[3][4] = {}, q[3][4] = {};
  #pragma unroll
  for (int k = 0; k < 2; ++k) {
    size_t idx = base + k * 256;
    float4 va = A4[idx], vp = P4[idx], vn = N4[idx];
    float ea[4] = {va.x, va.y, va.z, va.w};
    float ep[4] = {vp.x, vp.y, vp.z, vp.w};
    float en[4] = {vn.x, vn.y, vn.z, vn.w};
    #pragma unroll
    for (int f = 0; f < 4; ++f) {
      float x0 = ea[f] + EPS_IN; s[0][f] += x0; q[0][f] += x0 * x0;
      float x1 = ep[f] + EPS_IN; s[1][f] += x1; q[1][f] += x1 * x1;
      float x2 = en[f] + EPS_IN; s[2][f] += x2; q[2][f] += x2 * x2;
    }
  }
  #pragma unroll
  for (int g = 0; g < 3; ++g)
    #pragma unroll
    for (int f = 0; f < 4; ++f) {
      float vs = s[g][f], vq = q[g][f];
      vs += __shfl_xor(vs, 16); vs += __shfl_xor(vs, 32);
      vq += __shfl_xor(vq, 16); vq += __shfl_xor(vq, 32);
      s[g][f] = vs; q[g][f] = vq;
    }
  int lane = tid & 63;
  if (lane < 16) {
    int d0 = lane * 4;
    #pragma unroll
    for (int g = 0; g < 3; ++g)
      #pragma unroll
      for (int f = 0; f < 4; ++f) {
        atomicAdd(&acc[2 * g][d0 + f], s[g][f]);
        atomicAdd(&acc[2 * g + 1][d0 + f], q[g][f]);
      }
  }
  __syncthreads();
  for (int v = tid; v < 384; v += 256)
    atomicAdd(&stats[v], acc[v >> 6][v & 63]);
}

// ---------------------------------------------------------------------------
// Kernel B: inline inv_std from stats; build EHL rows [hi(64)|lo(64)] bf16,
// 16B chunks XOR-swizzled by row&7. Also pre-loads out with 8192*EPS_OUT.
// Grid: 2 pairs x 256 row-tiles (32 rows each) = 512 blocks x 256 threads.
__global__ __launch_bounds__(256) void prep_kernel(
    const float* __restrict__ a, const float* __restrict__ p,
    const float* __restrict__ n, const float* __restrict__ stats,
    unsigned short* __restrict__ EHL, float* __restrict__ out) {
  __shared__ float is_s[64];
  int pair = blockIdx.x >> 8;
  int tb   = blockIdx.x & 255;
  int tid  = threadIdx.x;
  if (tid < 32) out[blockIdx.x * 32 + tid] = 8192.0f * EPS_OUT;
  if (tid < 64) {
    float sa = stats[tid], qa = stats[64 + tid];
    float sb = pair ? stats[256 + tid] : stats[128 + tid];
    float qb = pair ? stats[320 + tid] : stats[192 + tid];
    const float invN = 1.0f / (float)NCO;
    float m = (sa + sb) * invN;
    float v = (qa + qb) * invN - m * m;
    is_s[tid] = 1.0f / sqrtf(v);
  }
  __syncthreads();
  const float* bptr = pair ? n : p;
  unsigned short* dst = EHL + (size_t)pair * EHL_PAIR_USHORTS;
  int c0 = tid & 7;          // chunk within row (8 bf16 = 16B)
  int rl = tid >> 3;         // row within block (0..31)
  int row = tb * 32 + rl;
  int d0 = c0 * 8;
  const float* ar = a    + (size_t)row * DFEAT + d0;
  const float* br = bptr + (size_t)row * DFEAT + d0;
  float4 a0 = *(const float4*)(ar);
  float4 a1 = *(const float4*)(ar + 4);
  float4 b0 = *(const float4*)(br);
  float4 b1 = *(const float4*)(br + 4);
  float e[8] = {a0.x - b0.x, a0.y - b0.y, a0.z - b0.z, a0.w - b0.w,
                a1.x - b1.x, a1.y - b1.y, a1.z - b1.z, a1.w - b1.w};
  u16x8 vh, vl;
  #pragma unroll
  for (int j = 0; j < 8; ++j) {
    float ej = e[j] * is_s[d0 + j];
    unsigned short hi = f2bf_rne(ej);
    vh[j] = hi;
    vl[j] = f2bf_rne(ej - bf2f(hi));
  }
  int cs = c0 ^ (row & 7);
  char* drow = (char*)dst + (size_t)row * 256;
  *(u16x8*)(drow + cs * 16)       = vh;   // hi chunk
  *(u16x8*)(drow + (8 + cs) * 16) = vl;   // lo chunk
}

// ---------------------------------------------------------------------------
// Kernel C: symmetric MFMA GEMM. Block = (pair, ib, half, squad): A tile ib (128
// rows) persistent in registers; for s = half+2*squad, +4, ... <= smax, process
// tile (ib, jb=(ib+s)&63) as two 64-row B substeps (16KB each, double-buffered).
// 4 waves (2x2), wave tile 64 rows x 32 cols, 48 MFMAs/substep (K=192).
// Grid: 512 blocks x 256 threads, LDS 64KB -> 2 blocks/CU.
#define GLOAD(gsrc, ldst)                                                  \
  __builtin_amdgcn_global_load_lds(                                        \
      (const __attribute__((address_space(1))) void*)(gsrc),               \
      (__attribute__((address_space(3))) void*)(ldst), 16, 0, 0)

__global__ __launch_bounds__(256, 2) void mdist_mfma(
    const unsigned short* __restrict__ EHL, float* __restrict__ out) {
  __shared__ __align__(16) unsigned char sA[32768];
  __shared__ __align__(16) unsigned char sB0[16384];
  __shared__ __align__(16) unsigned char sB1[16384];
  int bid = blockIdx.x;
  int sw  = (bid & 7) * 64 + (bid >> 3);   // bijective XCD swizzle (512 = 8*64)
  int pair  = sw >> 8;
  int ib    = (sw >> 2) & 63;
  int half  = (sw >> 1) & 1;
  int squad = sw & 1;
  const char* base = (const char*)(EHL + (size_t)pair * EHL_PAIR_USHORTS);
  const char* gA = base + (size_t)ib * 32768;
  int tid = threadIdx.x;
  int s0   = half + 2 * squad;             // 0..3
  int smax = (ib < 32) ? 32 : 31;
  int nT   = ((smax - s0) / 4 + 1) * 2;    // substeps: t -> (s = s0+4*(t>>1), sub = t&1)

  // prologue: A -> sA (32KB), substep 0 -> sB0 (16KB)
  {
    const char* gB0 = base + (size_t)(((ib + s0) & 63)) * 32768;
    #pragma unroll
    for (int r = 0; r < 8; ++r) {
      int off = r * 4096 + tid * 16;
      GLOAD(gA + off, sA + off);
    }
    #pragma unroll
    for (int r = 0; r < 4; ++r) {
      int off = r * 4096 + tid * 16;
      GLOAD(gB0 + off, sB0 + off);
    }
  }
  __syncthreads();

  int lane = tid & 63, w = tid >> 6;
  int wr = w >> 1, wc = w & 1;             // wave tile: rows wr*64, cols wc*32
  int l15 = lane & 15, lg = lane >> 4;

  // A fragments, resident for whole kernel: af[hk][m], hk = (half_sel<<1)|ks
  bf16x8 af[4][4];
  #pragma unroll
  for (int hk = 0; hk < 4; ++hk) {
    int c = ((hk >> 1) << 3) | ((hk & 1) << 2) | lg;
    #pragma unroll
    for (int m = 0; m < 4; ++m) {
      int r = wr * 64 + m * 16 + l15;
      int cs = c ^ (r & 7);
      af[hk][m] = *(const bf16x8*)(sA + r * 256 + cs * 16);
    }
  }

  float rs[4][4];
  #pragma unroll
  for (int m = 0; m < 4; ++m)
    #pragma unroll
    for (int r = 0; r < 4; ++r) rs[m][r] = 0.f;

  const f32x4 zacc = {0.f, 0.f, 0.f, 0.f};
  const int AH[3] = {0, 0, 1};
  const int BH[3] = {0, 1, 0};

  for (int t = 0; t < nT; ++t) {
    unsigned char* wbuf = (t & 1) ? sB0 : sB1;
    const unsigned char* rbuf = (t & 1) ? sB1 : sB0;
    int s   = s0 + 4 * (t >> 1);
    int sub = t & 1;
    if (t + 1 < nT) {
      int tn = t + 1;
      int sn = s0 + 4 * (tn >> 1);
      const char* gs = base + (size_t)((ib + sn) & 63) * 32768 + (tn & 1) * 16384;
      #pragma unroll
      for (int r = 0; r < 4; ++r) {
        int off = r * 4096 + tid * 16;
        GLOAD(gs + off, wbuf + off);
      }
    }
    // B fragments: rows are the substep's 64 local rows
    bf16x8 bf[4][2];
    #pragma unroll
    for (int hk = 0; hk < 4; ++hk) {
      int c = ((hk >> 1) << 3) | ((hk & 1) << 2) | lg;
      #pragma unroll
      for (int nn = 0; nn < 2; ++nn) {
        int r = wc * 32 + nn * 16 + l15;
        int cs = c ^ (r & 7);
        bf[hk][nn] = *(const bf16x8*)(rbuf + r * 256 + cs * 16);
      }
    }
    // 48 MFMAs, K=192, fresh accumulator each substep
    f32x4 acc[4][2];
    #pragma unroll
    for (int tt = 0; tt < 3; ++tt) {
      #pragma unroll
      for (int ks = 0; ks < 2; ++ks) {
        int ahk = (AH[tt] << 1) | ks;
        int bhk = (BH[tt] << 1) | ks;
        #pragma unroll
        for (int m = 0; m < 4; ++m) {
          #pragma unroll
          for (int nn = 0; nn < 2; ++nn)
            acc[m][nn] = __builtin_amdgcn_mfma_f32_16x16x32_bf16(
                af[ahk][m], bf[bhk][nn],
                (tt == 0 && ks == 0) ? zacc : acc[m][nn], 0, 0, 0);
        }
      }
    }
    // epilogue: f = sqrt(max(q,0)); rows always; cols for off-diag tiles
    if (s == 0) {
      #pragma unroll
      for (int m = 0; m < 4; ++m)
        #pragma unroll
        for (int nn = 0; nn < 2; ++nn)
          #pragma unroll
          for (int r = 0; r < 4; ++r)
            rs[m][r] += __builtin_amdgcn_sqrtf(fmaxf(acc[m][nn][r], 0.f));
    } else {
      float cq0 = 0.f, cq1 = 0.f;
      #pragma unroll
      for (int m = 0; m < 4; ++m)
        #pragma unroll
        for (int nn = 0; nn < 2; ++nn)
          #pragma unroll
          for (int r = 0; r < 4; ++r) {
            float f = __builtin_amdgcn_sqrtf(fmaxf(acc[m][nn][r], 0.f));
            rs[m][r] += f;
            if (nn == 0) cq0 += f; else cq1 += f;
          }
      cq0 += __shfl_xor(cq0, 16); cq0 += __shfl_xor(cq0, 32);
      cq1 += __shfl_xor(cq1, 16); cq1 += __shfl_xor(cq1, 32);
      if (lane < 16) {
        int jb = (ib + s) & 63;
        float* orow = &out[pair * BROWS + jb * 128 + sub * 64 + wc * 32 + l15];
        atomicAdd(orow, cq0);
        atomicAdd(orow + 16, cq1);
      }
    }
    __syncthreads();
  }

  // final row-sum reduce over the 16 col-lanes, one atomic per row per wave
  #pragma unroll
  for (int m = 0; m < 4; ++m)
    #pragma unroll
    for (int r = 0; r < 4; ++r) {
      float v = rs[m][r];
      v += __shfl_xor(v, 1);
      v += __shfl_xor(v, 2);
      v += __shfl_xor(v, 4);
      v += __shfl_xor(v, 8);
      rs[m][r] = v;
    }
  if (l15 == 0) {
    int i0 = ib * 128 + wr * 64;
    #pragma unroll
    for (int m = 0; m < 4; ++m)
      #pragma unroll
      for (int r = 0; r < 4; ++r)
        atomicAdd(&out[pair * BROWS + i0 + m * 16 + lg * 4 + r], rs[m][r]);
  }
}

// ---------------------------------------------------------------------------
extern "C" void kernel_launch(void* const* d_in, const int* in_sizes, int n_in,
                              void* d_out, int out_size, void* d_ws, size_t ws_size,
                              hipStream_t stream) {
  const float* anchor   = (const float*)d_in[0];
  const float* positive = (const float*)d_in[1];
  const float* negative = (const float*)d_in[2];
  float* out = (float*)d_out;
  float* ws  = (float*)d_ws;

  float* stats = ws;
  unsigned short* EHL = (unsigned short*)(ws + WS_EHL_F);

  hipMemsetAsync(stats, 0, 384 * sizeof(float), stream);
  stats_kernel<<<256, 256, 0, stream>>>(anchor, positive, negative, stats);
  prep_kernel<<<512, 256, 0, stream>>>(anchor, positive, negative, stats, EHL, out);
  mdist_mfma<<<512, 256, 0, stream>>>(EHL, out);
}

// Round 9
// 106.077 us; speedup vs baseline: 1.3719x; 1.0008x over previous
//
#include <hip/hip_runtime.h>
#include <hip/hip_bf16.h>

// MahalanobisDistanceLayer: B=8192, D=64.
// q = E @ E^T with E = (a-b) * rsqrt(var_per_feature(concat(a,b)+eps));
// out[i] = sum_j (q<0 ? 0 : sqrt(q)) + B*EPS_OUT for (anchor,positive), (anchor,negative).
//
// Split-bf16: E = Ehi + Elo. q ~= Ehi*Ehi^T + Ehi*Elo^T + Elo*Ehi^T -> K=192 bf16 GEMM.
// Symmetric scheme: per pair, 64 tiles of 128 rows; unordered tile pair {ib,(ib+s)&63}
// processed exactly once (s in [0,32], s=32 only for ib<32). Off-diag tiles contribute
// row-sums to ib-rows AND col-sums to jb-rows (f(q) symmetric) -> half the FLOPs.
// Pipeline: 3-buffer ring (sB0, sB1, sA-reuse), depth-2 prefetch, counted vmcnt(10),
// raw s_barrier (never drain vmcnt to 0 in the loop) -- T3+T4 minimum recipe.

typedef short bf16x8 __attribute__((ext_vector_type(8)));
typedef unsigned short u16x8 __attribute__((ext_vector_type(8)));
typedef float f32x4 __attribute__((ext_vector_type(4)));

#define BROWS 8192
#define DFEAT 64
#define NCO   16384
#define EPS_IN  1e-4f
#define EPS_OUT 1e-6f

// ---- workspace layout (bytes) ----
// [0, 1536)        : stats, 6 groups x 64 floats (Sa,Qa,Sp,Qp,Sn,Qn), atomic-accumulated
// [2048, 2048+4MB) : EHL, 2 pairs x 8192 rows x 128 bf16 (row = [hi(64)|lo(64)], 256B)
//                    16B-chunk index XOR-swizzled by (row&7)
#define WS_EHL_F 512
#define EHL_PAIR_USHORTS ((size_t)BROWS * 128)

static __device__ inline unsigned short f2bf_rne(float x) {
  unsigned u = __float_as_uint(x);
  unsigned r = (u + 0x7FFF + ((u >> 16) & 1)) >> 16;
  return (unsigned short)r;
}
static __device__ inline float bf2f(unsigned short s) {
  return __uint_as_float(((unsigned)s) << 16);
}

// ---------------------------------------------------------------------------
// Kernel A: per-feature sums / sums-of-squares, float4 loads, atomic into stats[384].
__global__ __launch_bounds__(256) void stats_kernel(
    const float* __restrict__ a, const float* __restrict__ p,
    const float* __restrict__ n, float* __restrict__ stats) {
  __shared__ float acc[6][64];
  int tid = threadIdx.x;
  for (int v = tid; v < 384; v += 256) acc[v >> 6][v & 63] = 0.f;
  __syncthreads();
  const float4* A4 = (const float4*)a;
  const float4* P4 = (const float4*)p;
  const float4* N4 = (const float4*)n;
  size_t base = (size_t)blockIdx.x * 512 + tid;
  float s[3][4] = {}, q[3][4] = {};
  #pragma unroll
  for (int k = 0; k < 2; ++k) {
    size_t idx = base + k * 256;
    float4 va = A4[idx], vp = P4[idx], vn = N4[idx];
    float ea[4] = {va.x, va.y, va.z, va.w};
    float ep[4] = {vp.x, vp.y, vp.z, vp.w};
    float en[4] = {vn.x, vn.y, vn.z, vn.w};
    #pragma unroll
    for (int f = 0; f < 4; ++f) {
      float x0 = ea[f] + EPS_IN; s[0][f] += x0; q[0][f] += x0 * x0;
      float x1 = ep[f] + EPS_IN; s[1][f] += x1; q[1][f] += x1 * x1;
      float x2 = en[f] + EPS_IN; s[2][f] += x2; q[2][f] += x2 * x2;
    }
  }
  #pragma unroll
  for (int g = 0; g < 3; ++g)
    #pragma unroll
    for (int f = 0; f < 4; ++f) {
      float vs = s[g][f], vq = q[g][f];
      vs += __shfl_xor(vs, 16); vs += __shfl_xor(vs, 32);
      vq += __shfl_xor(vq, 16); vq += __shfl_xor(vq, 32);
      s[g][f] = vs; q[g][f] = vq;
    }
  int lane = tid & 63;
  if (lane < 16) {
    int d0 = lane * 4;
    #pragma unroll
    for (int g = 0; g < 3; ++g)
      #pragma unroll
      for (int f = 0; f < 4; ++f) {
        atomicAdd(&acc[2 * g][d0 + f], s[g][f]);
        atomicAdd(&acc[2 * g + 1][d0 + f], q[g][f]);
      }
  }
  __syncthreads();
  for (int v = tid; v < 384; v += 256)
    atomicAdd(&stats[v], acc[v >> 6][v & 63]);
}

// ---------------------------------------------------------------------------
// Kernel B: inline inv_std from stats; build EHL rows [hi(64)|lo(64)] bf16,
// 16B chunks XOR-swizzled by row&7. Also pre-loads out with 8192*EPS_OUT.
// Grid: 2 pairs x 256 row-tiles (32 rows each) = 512 blocks x 256 threads.
__global__ __launch_bounds__(256) void prep_kernel(
    const float* __restrict__ a, const float* __restrict__ p,
    const float* __restrict__ n, const float* __restrict__ stats,
    unsigned short* __restrict__ EHL, float* __restrict__ out) {
  __shared__ float is_s[64];
  int pair = blockIdx.x >> 8;
  int tb   = blockIdx.x & 255;
  int tid  = threadIdx.x;
  if (tid < 32) out[blockIdx.x * 32 + tid] = 8192.0f * EPS_OUT;
  if (tid < 64) {
    float sa = stats[tid], qa = stats[64 + tid];
    float sb = pair ? stats[256 + tid] : stats[128 + tid];
    float qb = pair ? stats[320 + tid] : stats[192 + tid];
    const float invN = 1.0f / (float)NCO;
    float m = (sa + sb) * invN;
    float v = (qa + qb) * invN - m * m;
    is_s[tid] = 1.0f / sqrtf(v);
  }
  __syncthreads();
  const float* bptr = pair ? n : p;
  unsigned short* dst = EHL + (size_t)pair * EHL_PAIR_USHORTS;
  int c0 = tid & 7;          // chunk within row (8 bf16 = 16B)
  int rl = tid >> 3;         // row within block (0..31)
  int row = tb * 32 + rl;
  int d0 = c0 * 8;
  const float* ar = a    + (size_t)row * DFEAT + d0;
  const float* br = bptr + (size_t)row * DFEAT + d0;
  float4 a0 = *(const float4*)(ar);
  float4 a1 = *(const float4*)(ar + 4);
  float4 b0 = *(const float4*)(br);
  float4 b1 = *(const float4*)(br + 4);
  float e[8] = {a0.x - b0.x, a0.y - b0.y, a0.z - b0.z, a0.w - b0.w,
                a1.x - b1.x, a1.y - b1.y, a1.z - b1.z, a1.w - b1.w};
  u16x8 vh, vl;
  #pragma unroll
  for (int j = 0; j < 8; ++j) {
    float ej = e[j] * is_s[d0 + j];
    unsigned short hi = f2bf_rne(ej);
    vh[j] = hi;
    vl[j] = f2bf_rne(ej - bf2f(hi));
  }
  int cs = c0 ^ (row & 7);
  char* drow = (char*)dst + (size_t)row * 256;
  *(u16x8*)(drow + cs * 16)       = vh;   // hi chunk
  *(u16x8*)(drow + (8 + cs) * 16) = vl;   // lo chunk
}

// ---------------------------------------------------------------------------
// Kernel C: symmetric MFMA GEMM with depth-2 counted-vmcnt ring pipeline.
// Block = (pair, ib, half, squad); A tile (128 rows) persistent in registers;
// substeps t: s = s0+4*(t>>1), sub = t&1, 64 B-rows each (16KB), ring buffer t%3.
// 4 waves (2x2), wave tile 64 rows x 32 cols, 48 MFMAs/substep (K=192).
// Grid: 512 blocks x 256 threads, LDS 64KB -> 2 blocks/CU.
#define GLOAD(gsrc, ldst)                                                  \
  __builtin_amdgcn_global_load_lds(                                        \
      (const __attribute__((address_space(1))) void*)(gsrc),               \
      (__attribute__((address_space(3))) void*)(ldst), 16, 0, 0)

#define STAGE4(gs, ld)                                                     \
  do {                                                                     \
    _Pragma("unroll")                                                      \
    for (int r_ = 0; r_ < 4; ++r_) {                                       \
      int off_ = r_ * 4096 + tid * 16;                                     \
      GLOAD((gs) + off_, (ld) + off_);                                     \
    }                                                                      \
  } while (0)

__global__ __launch_bounds__(256, 2) void mdist_mfma(
    const unsigned short* __restrict__ EHL, float* __restrict__ out) {
  __shared__ __align__(16) unsigned char sA[32768];   // A tile; first 16KB reused as ring buf 2
  __shared__ __align__(16) unsigned char sB0[16384];
  __shared__ __align__(16) unsigned char sB1[16384];
  int bid = blockIdx.x;
  int sw  = (bid & 7) * 64 + (bid >> 3);   // bijective XCD swizzle (512 = 8*64)
  int pair  = sw >> 8;
  int ib    = (sw >> 2) & 63;
  int half  = (sw >> 1) & 1;
  int squad = sw & 1;
  const char* base = (const char*)(EHL + (size_t)pair * EHL_PAIR_USHORTS);
  const char* gA = base + (size_t)ib * 32768;
  int tid = threadIdx.x;
  int s0   = half + 2 * squad;             // 0..3
  int smax = (ib < 32) ? 32 : 31;
  int nT   = ((smax - s0) / 4 + 1) * 2;    // substeps (>= 16)

  auto gsrc = [&](int u) -> const char* {
    int s_  = s0 + 4 * (u >> 1);
    int jb_ = (ib + s_) & 63;
    return base + (size_t)jb_ * 32768 + (size_t)(u & 1) * 16384;
  };

  // prologue: A (8 loads/thread) -> sA, stage 0 -> sB0, stage 1 -> sB1
  #pragma unroll
  for (int r = 0; r < 8; ++r) {
    int off = r * 4096 + tid * 16;
    GLOAD(gA + off, sA + off);
  }
  STAGE4(gsrc(0), sB0);
  STAGE4(gsrc(1), sB1);
  asm volatile("s_waitcnt vmcnt(4)" ::: "memory");   // A + stage0 landed (stage1 in flight)
  __builtin_amdgcn_sched_barrier(0);
  __builtin_amdgcn_s_barrier();
  __builtin_amdgcn_sched_barrier(0);

  int lane = tid & 63, w = tid >> 6;
  int wr = w >> 1, wc = w & 1;             // wave tile: rows wr*64, cols wc*32
  int l15 = lane & 15, lg = lane >> 4;

  // A fragments, resident for whole kernel: af[hk][m], hk = (half_sel<<1)|ks
  bf16x8 af[4][4];
  #pragma unroll
  for (int hk = 0; hk < 4; ++hk) {
    int c = ((hk >> 1) << 3) | ((hk & 1) << 2) | lg;
    #pragma unroll
    for (int m = 0; m < 4; ++m) {
      int r = wr * 64 + m * 16 + l15;
      int cs = c ^ (r & 7);
      af[hk][m] = *(const bf16x8*)(sA + r * 256 + cs * 16);
    }
  }
  asm volatile("s_waitcnt lgkmcnt(0)" ::: "memory");  // all af reads done
  __builtin_amdgcn_sched_barrier(0);
  __builtin_amdgcn_s_barrier();
  __builtin_amdgcn_sched_barrier(0);
  STAGE4(gsrc(2), sA);                     // sA free -> ring buffer 2

  float rs[4][4];
  #pragma unroll
  for (int m = 0; m < 4; ++m)
    #pragma unroll
    for (int r = 0; r < 4; ++r) rs[m][r] = 0.f;

  const f32x4 zacc = {0.f, 0.f, 0.f, 0.f};
  const int AH[3] = {0, 0, 1};
  const int BH[3] = {0, 1, 0};

  unsigned char* r0 = sB0;
  unsigned char* r1 = sB1;
  unsigned char* r2 = sA;

  for (int t = 0; t < nT; ++t) {
    // stage t guaranteed landed: newer ops = 2 stages (8) + <=2 col-atomics = 10
    asm volatile("s_waitcnt vmcnt(10)" ::: "memory");
    __builtin_amdgcn_sched_barrier(0);
    __builtin_amdgcn_s_barrier();
    __builtin_amdgcn_sched_barrier(0);

    int s   = s0 + 4 * (t >> 1);
    int sub = t & 1;

    // B fragments from ring buffer r0 (compiler interleaves reads with MFMAs)
    bf16x8 bf[4][2];
    #pragma unroll
    for (int hk = 0; hk < 4; ++hk) {
      int c = ((hk >> 1) << 3) | ((hk & 1) << 2) | lg;
      #pragma unroll
      for (int nn = 0; nn < 2; ++nn) {
        int r = wc * 32 + nn * 16 + l15;
        int cs = c ^ (r & 7);
        bf[hk][nn] = *(const bf16x8*)(r0 + r * 256 + cs * 16);
      }
    }
    // 48 MFMAs, K=192, fresh accumulator each substep
    f32x4 acc[4][2];
    #pragma unroll
    for (int tt = 0; tt < 3; ++tt) {
      #pragma unroll
      for (int ks = 0; ks < 2; ++ks) {
        int ahk = (AH[tt] << 1) | ks;
        int bhk = (BH[tt] << 1) | ks;
        #pragma unroll
        for (int m = 0; m < 4; ++m) {
          #pragma unroll
          for (int nn = 0; nn < 2; ++nn)
            acc[m][nn] = __builtin_amdgcn_mfma_f32_16x16x32_bf16(
                af[ahk][m], bf[bhk][nn],
                (tt == 0 && ks == 0) ? zacc : acc[m][nn], 0, 0, 0);
        }
      }
    }

    // all waves done reading r0 -> safe to restage it (depth-2 prefetch)
    asm volatile("s_waitcnt lgkmcnt(0)" ::: "memory");
    __builtin_amdgcn_sched_barrier(0);
    __builtin_amdgcn_s_barrier();
    __builtin_amdgcn_sched_barrier(0);
    if (t + 3 < nT) STAGE4(gsrc(t + 3), r0);

    // epilogue: f = sqrt(max(q,0)); rows always; cols for off-diag tiles
    if (s == 0) {
      #pragma unroll
      for (int m = 0; m < 4; ++m)
        #pragma unroll
        for (int nn = 0; nn < 2; ++nn)
          #pragma unroll
          for (int r = 0; r < 4; ++r)
            rs[m][r] += __builtin_amdgcn_sqrtf(fmaxf(acc[m][nn][r], 0.f));
    } else {
      float cq0 = 0.f, cq1 = 0.f;
      #pragma unroll
      for (int m = 0; m < 4; ++m)
        #pragma unroll
        for (int nn = 0; nn < 2; ++nn)
          #pragma unroll
          for (int r = 0; r < 4; ++r) {
            float f = __builtin_amdgcn_sqrtf(fmaxf(acc[m][nn][r], 0.f));
            rs[m][r] += f;
            if (nn == 0) cq0 += f; else cq1 += f;
          }
      cq0 += __shfl_xor(cq0, 16); cq0 += __shfl_xor(cq0, 32);
      cq1 += __shfl_xor(cq1, 16); cq1 += __shfl_xor(cq1, 32);
      if (lane < 16) {
        int jb = (ib + s) & 63;
        float* orow = &out[pair * BROWS + jb * 128 + sub * 64 + wc * 32 + l15];
        atomicAdd(orow, cq0);
        atomicAdd(orow + 16, cq1);
      }
    }

    // rotate ring
    unsigned char* tmp = r0; r0 = r1; r1 = r2; r2 = tmp;
  }

  // final row-sum reduce over the 16 col-lanes, one atomic per row per wave
  #pragma unroll
  for (int m = 0; m < 4; ++m)
    #pragma unroll
    for (int r = 0; r < 4; ++r) {
      float v = rs[m][r];
      v += __shfl_xor(v, 1);
      v += __shfl_xor(v, 2);
      v += __shfl_xor(v, 4);
      v += __shfl_xor(v, 8);
      rs[m][r] = v;
    }
  if (l15 == 0) {
    int i0 = ib * 128 + wr * 64;
    #pragma unroll
    for (int m = 0; m < 4; ++m)
      #pragma unroll
      for (int r = 0; r < 4; ++r)
        atomicAdd(&out[pair * BROWS + i0 + m * 16 + lg * 4 + r], rs[m][r]);
  }
}

// ---------------------------------------------------------------------------
extern "C" void kernel_launch(void* const* d_in, const int* in_sizes, int n_in,
                              void* d_out, int out_size, void* d_ws, size_t ws_size,
                              hipStream_t stream) {
  const float* anchor   = (const float*)d_in[0];
  const float* positive = (const float*)d_in[1];
  const float* negative = (const float*)d_in[2];
  float* out = (float*)d_out;
  float* ws  = (float*)d_ws;

  float* stats = ws;
  unsigned short* EHL = (unsigned short*)(ws + WS_EHL_F);

  hipMemsetAsync(stats, 0, 384 * sizeof(float), stream);
  stats_kernel<<<256, 256, 0, stream>>>(anchor, positive, negative, stats);
  prep_kernel<<<512, 256, 0, stream>>>(anchor, positive, negative, stats, EHL, out);
  mdist_mfma<<<512, 256, 0, stream>>>(EHL, out);
}